// Round 11
// baseline (331.814 us; speedup 1.0000x reference)
//
#include <hip/hip_runtime.h>
#include <cstdint>
#include <cstddef>

// ---------------------------------------------------------------------------
// GAT 3-layer forward, MI355X.
// Round 11: revert round-10's manual prefetch (constrained compiler scheduling,
// 47->58 us regression). Attack the real limit per round-9 counters: grid cap
// (782 blocks = 3/CU = 12 waves/CU). gemm1 fout-split S=4 (FSUB=12, FT=3,
// 1564 blocks, 12.5 KB LDS); gemm2 S=5 (1955 blocks). Compiler-scheduled
// k-loop (constexpr trip) hoists loads with interleaved vmcnt waits.
// ---------------------------------------------------------------------------

__device__ __forceinline__ float leaky(float v) { return v > 0.f ? v : 0.2f * v; }

__device__ __forceinline__ unsigned short f2bf(float x) {
    unsigned int u = __float_as_uint(x);
    u = (u + 0x7FFFu + ((u >> 16) & 1u)) >> 16;   // RNE
    return (unsigned short)u;
}
__device__ __forceinline__ float bf2f(unsigned short b) {
    return __uint_as_float(((unsigned int)b) << 16);
}

#define BSHIFT 7                 // 128 nodes per bucket
#define BCAP   5120              // slots per bucket region (mean 4096, +16 sigma)
#define CTILE  8192              // edges per coarse block

// -------------------- coarse bin: edges -> bucket regions --------------------

__global__ __launch_bounds__(256) void coarse_bin_kernel(
    const int* __restrict__ ei, unsigned int* __restrict__ staged,
    int* __restrict__ gcursor, int E, int K) {
    __shared__ int hist[512];
    __shared__ int rank[512];
    __shared__ int base[512];
    for (int b = threadIdx.x; b < K; b += 256) { hist[b] = 0; rank[b] = 0; }
    __syncthreads();

    int e0 = blockIdx.x * CTILE;
    int e1 = min(E, e0 + CTILE);

    for (int e = e0 + threadIdx.x; e < e1; e += 256) {
        int d = ei[E + e];
        atomicAdd(&hist[d >> BSHIFT], 1);
    }
    __syncthreads();

    for (int b = threadIdx.x; b < K; b += 256) {
        int c = hist[b];
        base[b] = c ? atomicAdd(&gcursor[b], c) : 0;
    }
    __syncthreads();

    for (int e = e0 + threadIdx.x; e < e1; e += 256) {
        int s = ei[e];
        int d = ei[E + e];
        int b = d >> BSHIFT;
        int r = atomicAdd(&rank[b], 1);
        staged[(size_t)b * BCAP + base[b] + r] =
            ((unsigned int)(d & ((1 << BSHIFT) - 1)) << 16) | (unsigned int)s;
    }
}

// -------------------- bucket base scan (1 block) --------------------

__global__ __launch_bounds__(512) void bucket_scan_kernel(
    const int* __restrict__ gcursor, int* __restrict__ bbase, int K) {
    __shared__ int sh[512];
    int t = threadIdx.x;
    int v = (t < K) ? gcursor[t] : 0;
    sh[t] = v;
    __syncthreads();
    for (int off = 1; off < 512; off <<= 1) {
        int a = (t >= off) ? sh[t - off] : 0;
        __syncthreads();
        sh[t] += a;
        __syncthreads();
    }
    if (t < K) bbase[t] = sh[t] - v;   // exclusive
}

// -------------------- fine pass: bucket -> rowptr + sorted csr --------------------

__global__ __launch_bounds__(256) void fine_sort_kernel(
    const unsigned int* __restrict__ staged, const int* __restrict__ gcursor,
    const int* __restrict__ bbase, int* __restrict__ rowptr, int* __restrict__ csr,
    int N, int E) {
    __shared__ int cnt[128];
    __shared__ int off[128];
    __shared__ int lcsr[BCAP];
    const int b = blockIdx.x;
    const int t = threadIdx.x;
    const int c = gcursor[b];
    const int gb = bbase[b];
    const unsigned int* rec = staged + (size_t)b * BCAP;

    if (t < 128) cnt[t] = 0;
    __syncthreads();

    for (int i = t; i < c; i += 256) atomicAdd(&cnt[rec[i] >> 16], 1);
    __syncthreads();

    if (t < 128) off[t] = cnt[t];
    __syncthreads();
    for (int s = 1; s < 128; s <<= 1) {
        int a = (t >= s && t < 128) ? off[t - s] : 0;
        __syncthreads();
        if (t < 128) off[t] += a;
        __syncthreads();
    }

    if (t < 128) {
        int excl = off[t] - cnt[t];
        int n = (b << BSHIFT) + t;
        if (n <= N) rowptr[n] = gb + excl;
        cnt[t] = excl;
    }
    if (b == 0 && t == 0) rowptr[N] = E;
    __syncthreads();

    for (int i = t; i < c; i += 256) {
        unsigned int r = rec[i];
        int p = atomicAdd(&cnt[r >> 16], 1);
        lcsr[p] = (int)(r & 0xFFFFu);
    }
    __syncthreads();

    for (int i = t; i < c; i += 256) csr[gb + i] = lcsr[i];
}

// -------------------- fused GEMM + alpha (layers 1-2, bf16 H out) --------------------
// Grid (node_tiles, S). 256 threads = 64 node-slots x 4 quad lanes; thread owns
// M=2 nodes x FT = FSUB/4 fouts. Quad lanes share x float4 addresses; each Wt
// ds_read_b128 feeds M*4 FMAs. k-loop left to compiler scheduling (constexpr
// trip; it hoists independent loads). Alpha partials combined across
// fout-blocks via fp32 atomicAdd (pre-zeroed).

template <int FIN, int FOUT, int FSUB, int M>
__global__ __launch_bounds__(256) void gemm_alpha_kernel(
    const float* __restrict__ X, const float* __restrict__ W,
    const float* __restrict__ avs, const float* __restrict__ avd,
    unsigned short* __restrict__ hb, float* __restrict__ asrc, float* __restrict__ adst,
    int N) {
    constexpr int FT = FSUB / 4;
    static_assert(4 * FT == FSUB, "FSUB must be divisible by 4");
    constexpr int PITCH = FIN + 4;
    __shared__ float Wt[FSUB][PITCH];
    const int fbase = blockIdx.y * FSUB;
    for (int idx = threadIdx.x; idx < FSUB * FIN; idx += 256) {
        int k = idx % FIN, f = idx / FIN;
        Wt[f][k] = W[k * FOUT + fbase + f];
    }
    __syncthreads();

    const int j = threadIdx.x & 3;    // quad lane (fout subgroup)
    const int i = threadIdx.x >> 2;   // node slot (0..63)
    const int nbase = blockIdx.x * 64 * M + i * M;

    float acc[M][FT];
#pragma unroll
    for (int m = 0; m < M; m++)
#pragma unroll
        for (int c = 0; c < FT; c++) acc[m][c] = 0.f;

    const float* xrow[M];
#pragma unroll
    for (int m = 0; m < M; m++) {
        int n = nbase + m;
        if (n > N - 1) n = N - 1;    // clamp loads; stores guarded below
        xrow[m] = X + (size_t)n * FIN;
    }

    for (int k = 0; k < FIN; k += 4) {
        float4 xv[M];
#pragma unroll
        for (int m = 0; m < M; m++) xv[m] = *(const float4*)(xrow[m] + k);
#pragma unroll
        for (int c = 0; c < FT; c++) {
            float4 wv = *(const float4*)&Wt[j * FT + c][k];
#pragma unroll
            for (int m = 0; m < M; m++) {
                acc[m][c] = fmaf(xv[m].x, wv.x,
                             fmaf(xv[m].y, wv.y,
                              fmaf(xv[m].z, wv.z,
                               fmaf(xv[m].w, wv.w, acc[m][c]))));
            }
        }
    }

    float asv[FT], adv[FT];
#pragma unroll
    for (int c = 0; c < FT; c++) {
        asv[c] = avs[fbase + j * FT + c];
        adv[c] = avd[fbase + j * FT + c];
    }

#pragma unroll
    for (int m = 0; m < M; m++) {
        int n = nbase + m;
        float ps = 0.f, pd = 0.f;
#pragma unroll
        for (int c = 0; c < FT; c++) {
            ps = fmaf(acc[m][c], asv[c], ps);
            pd = fmaf(acc[m][c], adv[c], pd);
        }
        ps += __shfl_xor(ps, 1, 64); ps += __shfl_xor(ps, 2, 64);
        pd += __shfl_xor(pd, 1, 64); pd += __shfl_xor(pd, 2, 64);
        if (n < N) {
            if (j == 0) {
                atomicAdd(&asrc[n], ps);
                atomicAdd(&adst[n], pd);
            }
#pragma unroll
            for (int c = 0; c < FT; c++)
                hb[(size_t)n * 64 + fbase + j * FT + c] = f2bf(acc[m][c]);
        }
    }
}

// -------------------- aggregation layer 1 (FOUT=48, relu, writes act1) ----------

#define CHUNK 128

template <int FOUT, bool RELU>
__global__ __launch_bounds__(256) void agg_bf16_kernel(
    const int* __restrict__ rowptr, const int* __restrict__ csr,
    const float* __restrict__ asrc, const float* __restrict__ adst,
    const unsigned short* __restrict__ hb, const float* __restrict__ bias,
    float* __restrict__ OUT, int N) {
    __shared__ int2 wslds[4][CHUNK];   // {src, w bits}
    const int wv = threadIdx.x >> 6;
    int n = blockIdx.x * 4 + wv;
    if (n >= N) return;
    const int lane = threadIdx.x & 63;
    const int rs = rowptr[n], re = rowptr[n + 1];
    const float ad_n = adst[n];
    const float wself = __expf(leaky(asrc[n] + ad_n));
    const int fc = (lane < FOUT) ? lane : FOUT - 1;  // clamp: dup load, never stored

    float acc = wself * bf2f(hb[(size_t)n * 64 + fc]);
    float wpart = 0.f;

    for (int base = rs; base < re; base += CHUNK) {
        const int cnt = min(CHUNK, re - base);
        if (lane < cnt) {
            int s = csr[base + lane];
            float w = __expf(leaky(asrc[s] + ad_n));
            wpart += w;
            wslds[wv][lane] = make_int2(s, __float_as_int(w));
        }
        int i = 0;
        for (; i + 8 <= cnt; i += 8) {
            int2 p[8];
#pragma unroll
            for (int u = 0; u < 8; u++) p[u] = wslds[wv][i + u];
            float hv[8];
#pragma unroll
            for (int u = 0; u < 8; u++) hv[u] = bf2f(hb[(size_t)p[u].x * 64 + fc]);
#pragma unroll
            for (int u = 0; u < 8; u++) acc = fmaf(__int_as_float(p[u].y), hv[u], acc);
        }
        for (; i < cnt; i++) {
            int2 pp = wslds[wv][i];
            acc = fmaf(__int_as_float(pp.y), bf2f(hb[(size_t)pp.x * 64 + fc]), acc);
        }
    }

#pragma unroll
    for (int off = 32; off; off >>= 1) wpart += __shfl_xor(wpart, off, 64);
    float ssum = wpart + wself;

    if (lane < FOUT) {
        float o = acc / (ssum + 1e-16f) + bias[lane];
        if (RELU) o = fmaxf(o, 0.f);
        OUT[(size_t)n * FOUT + lane] = o;
    }
}

// -------------------- aggregation layer 2 fused with layer-3 GEMM --------------------

__global__ __launch_bounds__(256) void agg_bf16_h3_kernel(
    const int* __restrict__ rowptr, const int* __restrict__ csr,
    const float* __restrict__ asrc, const float* __restrict__ adst,
    const unsigned short* __restrict__ hb, const float* __restrict__ bias,
    const float* __restrict__ W3, float* __restrict__ h3, int N) {
    constexpr int FOUT = 60;
    __shared__ int2 wslds[4][CHUNK];
    const int wv = threadIdx.x >> 6;
    int n = blockIdx.x * 4 + wv;
    if (n >= N) return;
    const int lane = threadIdx.x & 63;
    const int rs = rowptr[n], re = rowptr[n + 1];
    const float ad_n = adst[n];
    const float wself = __expf(leaky(asrc[n] + ad_n));
    const int fc = (lane < FOUT) ? lane : FOUT - 1;

    float acc = wself * bf2f(hb[(size_t)n * 64 + fc]);
    float wpart = 0.f;

    for (int base = rs; base < re; base += CHUNK) {
        const int cnt = min(CHUNK, re - base);
        if (lane < cnt) {
            int s = csr[base + lane];
            float w = __expf(leaky(asrc[s] + ad_n));
            wpart += w;
            wslds[wv][lane] = make_int2(s, __float_as_int(w));
        }
        int i = 0;
        for (; i + 8 <= cnt; i += 8) {
            int2 p[8];
#pragma unroll
            for (int u = 0; u < 8; u++) p[u] = wslds[wv][i + u];
            float hv[8];
#pragma unroll
            for (int u = 0; u < 8; u++) hv[u] = bf2f(hb[(size_t)p[u].x * 64 + fc]);
#pragma unroll
            for (int u = 0; u < 8; u++) acc = fmaf(__int_as_float(p[u].y), hv[u], acc);
        }
        for (; i < cnt; i++) {
            int2 pp = wslds[wv][i];
            acc = fmaf(__int_as_float(pp.y), bf2f(hb[(size_t)pp.x * 64 + fc]), acc);
        }
    }

#pragma unroll
    for (int off = 32; off; off >>= 1) wpart += __shfl_xor(wpart, off, 64);
    float ssum = wpart + wself;

    // act2[n,lane] = relu(acc/ssum + bias); fold layer-3 GEMM: t = act2 * W3
    float t = 0.f;
    if (lane < FOUT) {
        float o = fmaxf(acc / (ssum + 1e-16f) + bias[lane], 0.f);
        t = o * W3[lane];
    }
#pragma unroll
    for (int off = 32; off; off >>= 1) t += __shfl_xor(t, off, 64);
    if (lane == 0) h3[n] = t;
}

// -------------------- layer-3 aggregation: alpha derived from h3 --------------------

__global__ __launch_bounds__(256) void agg1_kernel(
    const int* __restrict__ rowptr, const int* __restrict__ csr,
    const float* __restrict__ h3,
    const float* __restrict__ as3p, const float* __restrict__ ad3p,
    const float* __restrict__ bias, float* __restrict__ OUT, int N) {
    int n = blockIdx.x * 4 + (threadIdx.x >> 6);
    if (n >= N) return;
    int lane = threadIdx.x & 63;
    int rs = rowptr[n], re = rowptr[n + 1];
    const float a_s = as3p[0];
    float hn = h3[n];
    float adn = ad3p[0] * hn;
    float wself = __expf(leaky(a_s * hn + adn));

    float ssum = 0.f, accv = 0.f;
    for (int e = rs + lane; e < re; e += 64) {
        float hs = h3[csr[e]];
        float w = __expf(leaky(a_s * hs + adn));
        ssum += w;
        accv = fmaf(w, hs, accv);
    }
#pragma unroll
    for (int off = 32; off; off >>= 1) {
        ssum += __shfl_xor(ssum, off, 64);
        accv += __shfl_xor(accv, off, 64);
    }
    ssum += wself;
    accv = fmaf(wself, hn, accv);
    if (lane == 0) OUT[n] = accv / (ssum + 1e-16f) + bias[0];
}

// -------------------- host launcher --------------------

extern "C" void kernel_launch(void* const* d_in, const int* in_sizes, int n_in,
                              void* d_out, int out_size, void* d_ws, size_t ws_size,
                              hipStream_t stream) {
    const float* x      = (const float*)d_in[0];
    const int*   ei     = (const int*)d_in[1];   // int32 per harness convention
    // d_in[2] = edge_attr: ignored by reference (no edge_dim)
    const float* W1  = (const float*)d_in[3];
    const float* as1 = (const float*)d_in[4];
    const float* ad1 = (const float*)d_in[5];
    const float* b1  = (const float*)d_in[6];
    const float* W2  = (const float*)d_in[7];
    const float* as2 = (const float*)d_in[8];
    const float* ad2 = (const float*)d_in[9];
    const float* b2  = (const float*)d_in[10];
    const float* W3  = (const float*)d_in[11];
    const float* as3 = (const float*)d_in[12];
    const float* ad3 = (const float*)d_in[13];
    const float* b3  = (const float*)d_in[14];

    const int N = in_sizes[0] / 256;   // 50000
    const int E = in_sizes[1] / 2;     // 1600000
    const int K = (N + (1 << BSHIFT) - 1) >> BSHIFT;   // 391 buckets

    char* p = (char*)d_ws;
    auto alloc = [&](size_t bytes) -> void* {
        void* r = (void*)p;
        p += ((bytes + 255) / 256) * 256;
        return r;
    };
    int*   gcursor = (int*)alloc(512 * 4);
    int*   bbase   = (int*)alloc(512 * 4);
    int*   rowptr  = (int*)alloc(((size_t)N + 1) * 4);
    int*   csr     = (int*)alloc((size_t)E * 4);
    unsigned short* hb = (unsigned short*)alloc((size_t)N * 64 * 2);  // bf16 H, 128B rows
    float* actbuf  = (float*)alloc((size_t)N * 48 * 4);               // act1 only
    float* h3      = (float*)alloc((size_t)N * 4);
    float* asrc    = (float*)alloc((size_t)N * 4);
    float* adst    = (float*)alloc((size_t)N * 4);
    // staged bucket regions (8 MB) alias actbuf (9.6 MB, dead until first agg):
    unsigned int* staged = (unsigned int*)actbuf;

    // ---- CSR build (two-level bucketed counting sort) ----
    hipMemsetAsync(gcursor, 0, 512 * 4, stream);
    int cblocks = (E + CTILE - 1) / CTILE;
    coarse_bin_kernel<<<cblocks, 256, 0, stream>>>(ei, staged, gcursor, E, K);
    bucket_scan_kernel<<<1, 512, 0, stream>>>(gcursor, bbase, K);
    fine_sort_kernel<<<K, 256, 0, stream>>>(staged, gcursor, bbase, rowptr, csr, N, E);

    int gblocks = (N + 127) / 128;     // 128 nodes per block (M=2)
    int ablocks = (N + 3) / 4;

    // ---- layer 1: 256 -> 48, relu (fout-split S=4) ----
    hipMemsetAsync(asrc, 0, (size_t)N * 4, stream);
    hipMemsetAsync(adst, 0, (size_t)N * 4, stream);
    gemm_alpha_kernel<256, 48, 12, 2><<<dim3(gblocks, 4), 256, 0, stream>>>(
        x, W1, as1, ad1, hb, asrc, adst, N);
    agg_bf16_kernel<48, true><<<ablocks, 256, 0, stream>>>(rowptr, csr, asrc, adst, hb, b1, actbuf, N);

    // ---- layer 2: 48 -> 60, relu (fout-split S=5), fused layer-3 GEMM ----
    hipMemsetAsync(asrc, 0, (size_t)N * 4, stream);
    hipMemsetAsync(adst, 0, (size_t)N * 4, stream);
    gemm_alpha_kernel<48, 60, 12, 2><<<dim3(gblocks, 5), 256, 0, stream>>>(
        actbuf, W2, as2, ad2, hb, asrc, adst, N);
    agg_bf16_h3_kernel<<<ablocks, 256, 0, stream>>>(rowptr, csr, asrc, adst, hb, b2, W3, h3, N);

    // ---- layer 3 aggregation: straight to d_out ----
    agg1_kernel<<<ablocks, 256, 0, stream>>>(rowptr, csr, h3, as3, ad3, b3, (float*)d_out, N);
}

// Round 12
// 294.197 us; speedup vs baseline: 1.1279x; 1.1279x over previous
//
#include <hip/hip_runtime.h>
#include <cstdint>
#include <cstddef>

// ---------------------------------------------------------------------------
// GAT 3-layer forward, MI355X.
// Round 12: GEMM k-loop LDS traffic was the true plateau (R8-R11 all ~47-74us:
// ds_read_b128 12cyc/wave-inst on ONE LDS pipe/CU -> 24 waves/CU x 4.6k cyc
// = 47us exactly). New GEMM: lane = node, wave = fout-subset; W read via
// wave-uniform scalar loads (s_load -> v_fmac vacc, s_w, v_x), ZERO LDS in
// the k-loop; x loads perfectly coalesced float4. Alpha partials reduced
// across the 4 waves via 2KB LDS (no atomics, no memsets).
// ---------------------------------------------------------------------------

__device__ __forceinline__ float leaky(float v) { return v > 0.f ? v : 0.2f * v; }

__device__ __forceinline__ unsigned short f2bf(float x) {
    unsigned int u = __float_as_uint(x);
    u = (u + 0x7FFFu + ((u >> 16) & 1u)) >> 16;   // RNE
    return (unsigned short)u;
}
__device__ __forceinline__ float bf2f(unsigned short b) {
    return __uint_as_float(((unsigned int)b) << 16);
}

#define BSHIFT 7                 // 128 nodes per bucket
#define BCAP   5120              // slots per bucket region (mean 4096, +16 sigma)
#define CTILE  8192              // edges per coarse block

// -------------------- coarse bin: edges -> bucket regions --------------------

__global__ __launch_bounds__(256) void coarse_bin_kernel(
    const int* __restrict__ ei, unsigned int* __restrict__ staged,
    int* __restrict__ gcursor, int E, int K) {
    __shared__ int hist[512];
    __shared__ int rank[512];
    __shared__ int base[512];
    for (int b = threadIdx.x; b < K; b += 256) { hist[b] = 0; rank[b] = 0; }
    __syncthreads();

    int e0 = blockIdx.x * CTILE;
    int e1 = min(E, e0 + CTILE);

    for (int e = e0 + threadIdx.x; e < e1; e += 256) {
        int d = ei[E + e];
        atomicAdd(&hist[d >> BSHIFT], 1);
    }
    __syncthreads();

    for (int b = threadIdx.x; b < K; b += 256) {
        int c = hist[b];
        base[b] = c ? atomicAdd(&gcursor[b], c) : 0;
    }
    __syncthreads();

    for (int e = e0 + threadIdx.x; e < e1; e += 256) {
        int s = ei[e];
        int d = ei[E + e];
        int b = d >> BSHIFT;
        int r = atomicAdd(&rank[b], 1);
        staged[(size_t)b * BCAP + base[b] + r] =
            ((unsigned int)(d & ((1 << BSHIFT) - 1)) << 16) | (unsigned int)s;
    }
}

// -------------------- bucket base scan (1 block) --------------------

__global__ __launch_bounds__(512) void bucket_scan_kernel(
    const int* __restrict__ gcursor, int* __restrict__ bbase, int K) {
    __shared__ int sh[512];
    int t = threadIdx.x;
    int v = (t < K) ? gcursor[t] : 0;
    sh[t] = v;
    __syncthreads();
    for (int off = 1; off < 512; off <<= 1) {
        int a = (t >= off) ? sh[t - off] : 0;
        __syncthreads();
        sh[t] += a;
        __syncthreads();
    }
    if (t < K) bbase[t] = sh[t] - v;   // exclusive
}

// -------------------- fine pass: bucket -> rowptr + sorted csr --------------------

__global__ __launch_bounds__(256) void fine_sort_kernel(
    const unsigned int* __restrict__ staged, const int* __restrict__ gcursor,
    const int* __restrict__ bbase, int* __restrict__ rowptr, int* __restrict__ csr,
    int N, int E) {
    __shared__ int cnt[128];
    __shared__ int off[128];
    __shared__ int lcsr[BCAP];
    const int b = blockIdx.x;
    const int t = threadIdx.x;
    const int c = gcursor[b];
    const int gb = bbase[b];
    const unsigned int* rec = staged + (size_t)b * BCAP;

    if (t < 128) cnt[t] = 0;
    __syncthreads();

    for (int i = t; i < c; i += 256) atomicAdd(&cnt[rec[i] >> 16], 1);
    __syncthreads();

    if (t < 128) off[t] = cnt[t];
    __syncthreads();
    for (int s = 1; s < 128; s <<= 1) {
        int a = (t >= s && t < 128) ? off[t - s] : 0;
        __syncthreads();
        if (t < 128) off[t] += a;
        __syncthreads();
    }

    if (t < 128) {
        int excl = off[t] - cnt[t];
        int n = (b << BSHIFT) + t;
        if (n <= N) rowptr[n] = gb + excl;
        cnt[t] = excl;
    }
    if (b == 0 && t == 0) rowptr[N] = E;
    __syncthreads();

    for (int i = t; i < c; i += 256) {
        unsigned int r = rec[i];
        int p = atomicAdd(&cnt[r >> 16], 1);
        lcsr[p] = (int)(r & 0xFFFFu);
    }
    __syncthreads();

    for (int i = t; i < c; i += 256) csr[gb + i] = lcsr[i];
}

// -------------------- fused GEMM + alpha (layers 1-2, bf16 H out) --------------------
// lane = node (64 nodes/block); wave wid handles fouts [wid*FT, (wid+1)*FT).
// W accessed with wave-uniform indices (readfirstlane-pinned wid) -> scalar
// loads + v_fmac with SGPR operand. No LDS in the k-loop. x float4 loads are
// fully coalesced (lane n -> row n). Alpha: per-wave partials reduced across
// the 4 waves via small LDS; wave 0 writes asrc/adst (no atomics).

template <int FIN, int FOUT, int FT>
__global__ __launch_bounds__(256) void gemm_sgpr_kernel(
    const float* __restrict__ X, const float* __restrict__ W,
    const float* __restrict__ avs, const float* __restrict__ avd,
    unsigned short* __restrict__ hb, float* __restrict__ asrc, float* __restrict__ adst,
    int N) {
    static_assert(4 * FT == FOUT, "FT must be FOUT/4");
    __shared__ float red[2][4][64];

    const int wid  = __builtin_amdgcn_readfirstlane(threadIdx.x >> 6); // wave id 0..3
    const int lane = threadIdx.x & 63;
    const int n    = blockIdx.x * 64 + lane;
    const int nc   = (n < N) ? n : N - 1;     // clamp loads; stores guarded
    const int fbase = wid * FT;               // uniform

    const float* xrow = X + (size_t)nc * FIN;

    float acc[FT];
#pragma unroll
    for (int c = 0; c < FT; c++) acc[c] = 0.f;

#pragma unroll
    for (int k = 0; k < FIN; k += 4) {
        float4 xv = *(const float4*)(xrow + k);
        const float* w0 = W + (size_t)k * FOUT + fbase;   // uniform base
#pragma unroll
        for (int c = 0; c < FT; c++) {
            acc[c] = fmaf(xv.x, w0[c],            acc[c]);
            acc[c] = fmaf(xv.y, w0[FOUT + c],     acc[c]);
            acc[c] = fmaf(xv.z, w0[2 * FOUT + c], acc[c]);
            acc[c] = fmaf(xv.w, w0[3 * FOUT + c], acc[c]);
        }
    }

    // alpha partials over this wave's fout subset (avs/avd loads are uniform)
    float ps = 0.f, pd = 0.f;
#pragma unroll
    for (int c = 0; c < FT; c++) {
        ps = fmaf(acc[c], avs[fbase + c], ps);
        pd = fmaf(acc[c], avd[fbase + c], pd);
    }
    red[0][wid][lane] = ps;
    red[1][wid][lane] = pd;

    // h store (bf16, padded 64-entry rows)
    if (n < N) {
        if constexpr ((FT & 1) == 0) {
            unsigned int* dst = (unsigned int*)(hb + (size_t)n * 64 + fbase);
#pragma unroll
            for (int c = 0; c < FT; c += 2) {
                unsigned int pk = (unsigned int)f2bf(acc[c]) |
                                  ((unsigned int)f2bf(acc[c + 1]) << 16);
                dst[c >> 1] = pk;
            }
        } else {
#pragma unroll
            for (int c = 0; c < FT; c++)
                hb[(size_t)n * 64 + fbase + c] = f2bf(acc[c]);
        }
    }

    __syncthreads();
    if (threadIdx.x < 64 && n < N) {
        float s = red[0][0][lane] + red[0][1][lane] + red[0][2][lane] + red[0][3][lane];
        float d = red[1][0][lane] + red[1][1][lane] + red[1][2][lane] + red[1][3][lane];
        asrc[n] = s;
        adst[n] = d;
    }
}

// -------------------- aggregation layer 1 (FOUT=48, relu, writes act1) ----------

#define CHUNK 128

template <int FOUT, bool RELU>
__global__ __launch_bounds__(256) void agg_bf16_kernel(
    const int* __restrict__ rowptr, const int* __restrict__ csr,
    const float* __restrict__ asrc, const float* __restrict__ adst,
    const unsigned short* __restrict__ hb, const float* __restrict__ bias,
    float* __restrict__ OUT, int N) {
    __shared__ int2 wslds[4][CHUNK];   // {src, w bits}
    const int wv = threadIdx.x >> 6;
    int n = blockIdx.x * 4 + wv;
    if (n >= N) return;
    const int lane = threadIdx.x & 63;
    const int rs = rowptr[n], re = rowptr[n + 1];
    const float ad_n = adst[n];
    const float wself = __expf(leaky(asrc[n] + ad_n));
    const int fc = (lane < FOUT) ? lane : FOUT - 1;  // clamp: dup load, never stored

    float acc = wself * bf2f(hb[(size_t)n * 64 + fc]);
    float wpart = 0.f;

    for (int base = rs; base < re; base += CHUNK) {
        const int cnt = min(CHUNK, re - base);
        if (lane < cnt) {
            int s = csr[base + lane];
            float w = __expf(leaky(asrc[s] + ad_n));
            wpart += w;
            wslds[wv][lane] = make_int2(s, __float_as_int(w));
        }
        int i = 0;
        for (; i + 8 <= cnt; i += 8) {
            int2 p[8];
#pragma unroll
            for (int u = 0; u < 8; u++) p[u] = wslds[wv][i + u];
            float hv[8];
#pragma unroll
            for (int u = 0; u < 8; u++) hv[u] = bf2f(hb[(size_t)p[u].x * 64 + fc]);
#pragma unroll
            for (int u = 0; u < 8; u++) acc = fmaf(__int_as_float(p[u].y), hv[u], acc);
        }
        for (; i < cnt; i++) {
            int2 pp = wslds[wv][i];
            acc = fmaf(__int_as_float(pp.y), bf2f(hb[(size_t)pp.x * 64 + fc]), acc);
        }
    }

#pragma unroll
    for (int off = 32; off; off >>= 1) wpart += __shfl_xor(wpart, off, 64);
    float ssum = wpart + wself;

    if (lane < FOUT) {
        float o = acc / (ssum + 1e-16f) + bias[lane];
        if (RELU) o = fmaxf(o, 0.f);
        OUT[(size_t)n * FOUT + lane] = o;
    }
}

// -------------------- aggregation layer 2 fused with layer-3 GEMM --------------------

__global__ __launch_bounds__(256) void agg_bf16_h3_kernel(
    const int* __restrict__ rowptr, const int* __restrict__ csr,
    const float* __restrict__ asrc, const float* __restrict__ adst,
    const unsigned short* __restrict__ hb, const float* __restrict__ bias,
    const float* __restrict__ W3, float* __restrict__ h3, int N) {
    constexpr int FOUT = 60;
    __shared__ int2 wslds[4][CHUNK];
    const int wv = threadIdx.x >> 6;
    int n = blockIdx.x * 4 + wv;
    if (n >= N) return;
    const int lane = threadIdx.x & 63;
    const int rs = rowptr[n], re = rowptr[n + 1];
    const float ad_n = adst[n];
    const float wself = __expf(leaky(asrc[n] + ad_n));
    const int fc = (lane < FOUT) ? lane : FOUT - 1;

    float acc = wself * bf2f(hb[(size_t)n * 64 + fc]);
    float wpart = 0.f;

    for (int base = rs; base < re; base += CHUNK) {
        const int cnt = min(CHUNK, re - base);
        if (lane < cnt) {
            int s = csr[base + lane];
            float w = __expf(leaky(asrc[s] + ad_n));
            wpart += w;
            wslds[wv][lane] = make_int2(s, __float_as_int(w));
        }
        int i = 0;
        for (; i + 8 <= cnt; i += 8) {
            int2 p[8];
#pragma unroll
            for (int u = 0; u < 8; u++) p[u] = wslds[wv][i + u];
            float hv[8];
#pragma unroll
            for (int u = 0; u < 8; u++) hv[u] = bf2f(hb[(size_t)p[u].x * 64 + fc]);
#pragma unroll
            for (int u = 0; u < 8; u++) acc = fmaf(__int_as_float(p[u].y), hv[u], acc);
        }
        for (; i < cnt; i++) {
            int2 pp = wslds[wv][i];
            acc = fmaf(__int_as_float(pp.y), bf2f(hb[(size_t)pp.x * 64 + fc]), acc);
        }
    }

#pragma unroll
    for (int off = 32; off; off >>= 1) wpart += __shfl_xor(wpart, off, 64);
    float ssum = wpart + wself;

    // act2[n,lane] = relu(acc/ssum + bias); fold layer-3 GEMM: t = act2 * W3
    float t = 0.f;
    if (lane < FOUT) {
        float o = fmaxf(acc / (ssum + 1e-16f) + bias[lane], 0.f);
        t = o * W3[lane];
    }
#pragma unroll
    for (int off = 32; off; off >>= 1) t += __shfl_xor(t, off, 64);
    if (lane == 0) h3[n] = t;
}

// -------------------- layer-3 aggregation: alpha derived from h3 --------------------

__global__ __launch_bounds__(256) void agg1_kernel(
    const int* __restrict__ rowptr, const int* __restrict__ csr,
    const float* __restrict__ h3,
    const float* __restrict__ as3p, const float* __restrict__ ad3p,
    const float* __restrict__ bias, float* __restrict__ OUT, int N) {
    int n = blockIdx.x * 4 + (threadIdx.x >> 6);
    if (n >= N) return;
    int lane = threadIdx.x & 63;
    int rs = rowptr[n], re = rowptr[n + 1];
    const float a_s = as3p[0];
    float hn = h3[n];
    float adn = ad3p[0] * hn;
    float wself = __expf(leaky(a_s * hn + adn));

    float ssum = 0.f, accv = 0.f;
    for (int e = rs + lane; e < re; e += 64) {
        float hs = h3[csr[e]];
        float w = __expf(leaky(a_s * hs + adn));
        ssum += w;
        accv = fmaf(w, hs, accv);
    }
#pragma unroll
    for (int off = 32; off; off >>= 1) {
        ssum += __shfl_xor(ssum, off, 64);
        accv += __shfl_xor(accv, off, 64);
    }
    ssum += wself;
    accv = fmaf(wself, hn, accv);
    if (lane == 0) OUT[n] = accv / (ssum + 1e-16f) + bias[0];
}

// -------------------- host launcher --------------------

extern "C" void kernel_launch(void* const* d_in, const int* in_sizes, int n_in,
                              void* d_out, int out_size, void* d_ws, size_t ws_size,
                              hipStream_t stream) {
    const float* x      = (const float*)d_in[0];
    const int*   ei     = (const int*)d_in[1];   // int32 per harness convention
    // d_in[2] = edge_attr: ignored by reference (no edge_dim)
    const float* W1  = (const float*)d_in[3];
    const float* as1 = (const float*)d_in[4];
    const float* ad1 = (const float*)d_in[5];
    const float* b1  = (const float*)d_in[6];
    const float* W2  = (const float*)d_in[7];
    const float* as2 = (const float*)d_in[8];
    const float* ad2 = (const float*)d_in[9];
    const float* b2  = (const float*)d_in[10];
    const float* W3  = (const float*)d_in[11];
    const float* as3 = (const float*)d_in[12];
    const float* ad3 = (const float*)d_in[13];
    const float* b3  = (const float*)d_in[14];

    const int N = in_sizes[0] / 256;   // 50000
    const int E = in_sizes[1] / 2;     // 1600000
    const int K = (N + (1 << BSHIFT) - 1) >> BSHIFT;   // 391 buckets

    char* p = (char*)d_ws;
    auto alloc = [&](size_t bytes) -> void* {
        void* r = (void*)p;
        p += ((bytes + 255) / 256) * 256;
        return r;
    };
    int*   gcursor = (int*)alloc(512 * 4);
    int*   bbase   = (int*)alloc(512 * 4);
    int*   rowptr  = (int*)alloc(((size_t)N + 1) * 4);
    int*   csr     = (int*)alloc((size_t)E * 4);
    unsigned short* hb = (unsigned short*)alloc((size_t)N * 64 * 2);  // bf16 H, 128B rows
    float* actbuf  = (float*)alloc((size_t)N * 48 * 4);               // act1 only
    float* h3      = (float*)alloc((size_t)N * 4);
    float* asrc    = (float*)alloc((size_t)N * 4);
    float* adst    = (float*)alloc((size_t)N * 4);
    // staged bucket regions (8 MB) alias actbuf (9.6 MB, dead until first agg):
    unsigned int* staged = (unsigned int*)actbuf;

    // ---- CSR build (two-level bucketed counting sort) ----
    hipMemsetAsync(gcursor, 0, 512 * 4, stream);
    int cblocks = (E + CTILE - 1) / CTILE;
    coarse_bin_kernel<<<cblocks, 256, 0, stream>>>(ei, staged, gcursor, E, K);
    bucket_scan_kernel<<<1, 512, 0, stream>>>(gcursor, bbase, K);
    fine_sort_kernel<<<K, 256, 0, stream>>>(staged, gcursor, bbase, rowptr, csr, N, E);

    int gblocks = (N + 63) / 64;       // 64 nodes per block (lane = node)
    int ablocks = (N + 3) / 4;

    // ---- layer 1: 256 -> 48, relu ----
    gemm_sgpr_kernel<256, 48, 12><<<gblocks, 256, 0, stream>>>(
        x, W1, as1, ad1, hb, asrc, adst, N);
    agg_bf16_kernel<48, true><<<ablocks, 256, 0, stream>>>(rowptr, csr, asrc, adst, hb, b1, actbuf, N);

    // ---- layer 2: 48 -> 60, relu, fused layer-3 GEMM in agg epilogue ----
    gemm_sgpr_kernel<48, 60, 15><<<gblocks, 256, 0, stream>>>(
        actbuf, W2, as2, ad2, hb, asrc, adst, N);
    agg_bf16_h3_kernel<<<ablocks, 256, 0, stream>>>(rowptr, csr, asrc, adst, hb, b2, W3, h3, N);

    // ---- layer 3 aggregation: straight to d_out ----
    agg1_kernel<<<ablocks, 256, 0, stream>>>(rowptr, csr, h3, as3, ad3, b3, (float*)d_out, N);
}